// Round 8
// baseline (143.334 us; speedup 1.0000x reference)
//
#include <hip/hip_runtime.h>
#include <hip/hip_cooperative_groups.h>
#include <hip/hip_bf16.h>

namespace cg = cooperative_groups;

// ---------------------------------------------------------------------------
// Closed-form bilaplacian of f(x) = W3 tanh(W2 tanh(W1 x + b1) + b2) + b3.
//   c_k[n] = phi^(k)(u0)_n ; E_k[m] = W3_m phi^(k)(v0)_m
//   A = W1 (256x64); P = W2 diag(c1) W1; G = A A^T; T = P A^T; r2 = row|A|^2
// per-m: p2=|P_m|^2; q=W2(c2 r2); s5=W2(c4 r2^2); s3=sum c2 W2 T^2;
//        s4=sum c3 r2 W2 T; u=s^T(G.*G)s, s=c2*W2row.
// Delta^2 f = sum_m E4 p2^2 + E3(2 q p2 + 4 s3) + E2(q^2 + 2u + 4 s4) + E1 s5
//
// Single cooperative kernel, 32 blocks x 256:
//   phase1: Gram(0-15) | P+p2(16-23, local c1) | E/q/s5(24-27, local coefs)
//           | c-vectors + zero U/S3/S4 (28)
//   phase2: u-GEMM(0-15) | T-tiles s3/s4(16-31)
//   phase3: block 0 combines -> out
// ---------------------------------------------------------------------------

// ws float offsets (ws_f = d_ws + 16 bytes)
#define C_F    0        // c1..c4 [4][256]
#define R2_F   1280
#define E_F    1536     // E1..E4 [4][256]
#define Q_F    2560
#define S5_F   2816
#define U_F    3072
#define S3_F   3328
#define S4_F   3584
#define P2_F   3840
#define G_F    4096     // [256][256]
#define P_F    69632    // [256][64]

__global__ __launch_bounds__(256) void fused_kernel(
    const float* __restrict__ x,  const float* __restrict__ W1,
    const float* __restrict__ b1, const float* __restrict__ W2,
    const float* __restrict__ b2, const float* __restrict__ W3,
    float* __restrict__ ws_f, float* __restrict__ out) {
    cg::grid_group grid = cg::this_grid();
    __shared__ __align__(16) float smem[13248];
    __shared__ double dsum[4];
    int tid = threadIdx.x, b = blockIdx.x;

    // ================= phase 1 =================
    if (b < 16) {                     // ---- Gram tiles G = W1 W1^T
        int nb = b >> 2, pb = b & 3;
        float* As = smem;
        float* Bs = smem + 4352;
        for (int idx = tid; idx < 4096; idx += 256) {
            int r = idx >> 6, i = idx & 63;
            As[i * 68 + r] = W1[(nb * 64 + r) * 64 + i];
            Bs[i * 68 + r] = W1[(pb * 64 + r) * 64 + i];
        }
        __syncthreads();
        int r0 = (tid & 15) * 4, c0 = (tid >> 4) * 4;
        float a[4][4] = {};
        for (int i = 0; i < 64; i++) {
            float4 av = *(const float4*)&As[i * 68 + r0];
            float4 bv = *(const float4*)&Bs[i * 68 + c0];
            float ar[4] = {av.x, av.y, av.z, av.w};
            float br[4] = {bv.x, bv.y, bv.z, bv.w};
            #pragma unroll
            for (int rr = 0; rr < 4; rr++)
                #pragma unroll
                for (int cc = 0; cc < 4; cc++)
                    a[rr][cc] = fmaf(ar[rr], br[cc], a[rr][cc]);
        }
        float* G = ws_f + G_F;
        #pragma unroll
        for (int rr = 0; rr < 4; rr++)
            #pragma unroll
            for (int cc = 0; cc < 4; cc++)
                G[(nb * 64 + r0 + rr) * 256 + pb * 64 + c0 + cc] = a[rr][cc];
    } else if (b < 24) {              // ---- P = W2 diag(c1) W1 (+p2), local c1
        int m0 = (b - 16) * 32;
        float* Wc  = smem;            // [64n][34]
        float* Bc  = smem + 2176;     // [64n][68]
        float* c1s = smem + 6528;     // 256
        float* xs  = smem + 6784;     // 64
        if (tid < 64) xs[tid] = x[tid];
        __syncthreads();
        {
            const float4* row = (const float4*)(W1 + tid * 64);
            const float4* xv4 = (const float4*)xs;
            float u0 = b1[tid];
            #pragma unroll
            for (int k = 0; k < 16; k++) {
                float4 w = row[k], xv = xv4[k];
                u0 += w.x * xv.x + w.y * xv.y + w.z * xv.z + w.w * xv.w;
            }
            float T = tanhf(u0);
            c1s[tid] = 1.f - T * T;
        }
        float acc2[2][4] = {};
        int tm2 = (tid & 15) * 2, ti = (tid >> 4) * 4;
        for (int nc = 0; nc < 4; nc++) {
            __syncthreads();
            for (int idx = tid; idx < 2048; idx += 256) {
                int mm = idx >> 6, nn = idx & 63;
                Wc[nn * 34 + mm] = W2[(m0 + mm) * 256 + nc * 64 + nn];
            }
            for (int idx = tid; idx < 4096; idx += 256) {
                int nn = idx >> 6, ii = idx & 63, n = nc * 64 + nn;
                Bc[nn * 68 + ii] = c1s[n] * W1[n * 64 + ii];
            }
            __syncthreads();
            for (int nn = 0; nn < 64; nn++) {
                float2 a2 = *(const float2*)&Wc[nn * 34 + tm2];
                float4 b4 = *(const float4*)&Bc[nn * 68 + ti];
                float br[4] = {b4.x, b4.y, b4.z, b4.w};
                #pragma unroll
                for (int j = 0; j < 4; j++) {
                    acc2[0][j] = fmaf(a2.x, br[j], acc2[0][j]);
                    acc2[1][j] = fmaf(a2.y, br[j], acc2[1][j]);
                }
            }
        }
        float* P = ws_f + P_F;
        float s0 = 0.f, s1 = 0.f;
        #pragma unroll
        for (int j = 0; j < 4; j++) {
            P[(m0 + tm2) * 64 + ti + j]     = acc2[0][j];
            P[(m0 + tm2 + 1) * 64 + ti + j] = acc2[1][j];
            s0 += acc2[0][j] * acc2[0][j];
            s1 += acc2[1][j] * acc2[1][j];
        }
        __syncthreads();
        float* red = smem;            // [32][16]
        red[tm2 * 16 + (tid >> 4)]       = s0;
        red[(tm2 + 1) * 16 + (tid >> 4)] = s1;
        __syncthreads();
        if (tid < 32) {
            float p = 0.f;
            #pragma unroll
            for (int g = 0; g < 16; g++) p += red[tid * 16 + g];
            ws_f[P2_F + m0 + tid] = p;
        }
    } else if (b < 28) {              // ---- E, q, s5 (local coefs)
        int m0 = (b - 24) * 64;
        float* Ws   = smem;           // [64n][65]
        float* h0s  = smem + 4160;
        float* aqs  = smem + 4416;
        float* a5s  = smem + 4672;
        float* part = smem + 4928;    // [3][256]
        float* xs   = smem + 5696;    // 64
        if (tid < 64) xs[tid] = x[tid];
        __syncthreads();
        {
            const float4* row = (const float4*)(W1 + tid * 64);
            const float4* xv4 = (const float4*)xs;
            float u0 = b1[tid], r2v = 0.f;
            #pragma unroll
            for (int k = 0; k < 16; k++) {
                float4 w = row[k], xv = xv4[k];
                u0  += w.x * xv.x + w.y * xv.y + w.z * xv.z + w.w * xv.w;
                r2v += w.x * w.x + w.y * w.y + w.z * w.z + w.w * w.w;
            }
            float T = tanhf(u0), s = 1.f - T * T;
            float c2 = -2.f * T * s;
            float c4 = s * T * (16.f - 24.f * T * T);
            h0s[tid] = T;
            aqs[tid] = c2 * r2v;
            a5s[tid] = c4 * r2v * r2v;
        }
        int mm = tid & 63, nq = tid >> 6;
        float pv = 0.f, pq = 0.f, p5 = 0.f;
        for (int nc = 0; nc < 4; nc++) {
            __syncthreads();
            for (int idx = tid; idx < 4096; idx += 256) {
                int m2 = idx >> 6, nn = idx & 63;
                Ws[nn * 65 + m2] = W2[(m0 + m2) * 256 + nc * 64 + nn];
            }
            __syncthreads();
            #pragma unroll
            for (int k = 0; k < 16; k++) {
                int nn = nq * 16 + k, n = nc * 64 + nn;
                float wv = Ws[nn * 65 + mm];
                pv = fmaf(wv, h0s[n], pv);
                pq = fmaf(wv, aqs[n], pq);
                p5 = fmaf(wv, a5s[n], p5);
            }
        }
        part[nq * 64 + mm]       = pv;
        part[256 + nq * 64 + mm] = pq;
        part[512 + nq * 64 + mm] = p5;
        __syncthreads();
        if (tid < 64) {
            int m = m0 + tid;
            float v  = b2[m] + part[tid] + part[64 + tid] + part[128 + tid] + part[192 + tid];
            float q  = part[256 + tid] + part[320 + tid] + part[384 + tid] + part[448 + tid];
            float s5 = part[512 + tid] + part[576 + tid] + part[640 + tid] + part[704 + tid];
            float T2 = tanhf(v), s2 = 1.f - T2 * T2, w3 = W3[m];
            float* E = ws_f + E_F;
            E[m]       = w3 * s2;
            E[256 + m] = -2.f * w3 * T2 * s2;
            E[512 + m] = w3 * s2 * (6.f * T2 * T2 - 2.f);
            E[768 + m] = w3 * s2 * T2 * (16.f - 24.f * T2 * T2);
            ws_f[Q_F + m]  = q;
            ws_f[S5_F + m] = s5;
        }
    } else if (b == 28) {             // ---- c-vectors to ws + zero U/S3/S4
        float* xs = smem;
        if (tid < 64) xs[tid] = x[tid];
        __syncthreads();
        const float4* row = (const float4*)(W1 + tid * 64);
        const float4* xv4 = (const float4*)xs;
        float u0 = b1[tid], r2v = 0.f;
        #pragma unroll
        for (int k = 0; k < 16; k++) {
            float4 w = row[k], xv = xv4[k];
            u0  += w.x * xv.x + w.y * xv.y + w.z * xv.z + w.w * xv.w;
            r2v += w.x * w.x + w.y * w.y + w.z * w.z + w.w * w.w;
        }
        float T = tanhf(u0), s = 1.f - T * T;
        ws_f[C_F + tid]       = s;
        ws_f[C_F + 256 + tid] = -2.f * T * s;
        ws_f[C_F + 512 + tid] = s * (6.f * T * T - 2.f);
        ws_f[C_F + 768 + tid] = s * T * (16.f - 24.f * T * T);
        ws_f[R2_F + tid] = r2v;
        ws_f[U_F  + tid] = 0.f;
        ws_f[S3_F + tid] = 0.f;
        ws_f[S4_F + tid] = 0.f;
    }
    __threadfence();
    grid.sync();

    // ================= phase 2 =================
    if (b < 16) {                     // ---- u-GEMM: Yt=(G.*G diag(c2))W2^T
        int kb = b >> 2, mb = b & 3;
        const float* c2g = ws_f + C_F + 256;
        float* As  = smem;            // [nn][68]
        float* Bs  = smem + 4352;     // [nn][68]
        float* W2k = smem + 8704;     // [mm][68]
        float* c2k = smem + 13056;    // 64
        for (int idx = tid; idx < 4096; idx += 256) {
            int a_ = idx >> 6, b_ = idx & 63;
            W2k[a_ * 68 + b_] = W2[(mb * 64 + a_) * 256 + kb * 64 + b_];
        }
        if (tid < 64) c2k[tid] = c2g[kb * 64 + tid];
        int r0 = (tid & 15) * 4, c0 = (tid >> 4) * 4;
        float a[4][4] = {};
        const float* G = ws_f + G_F;
        for (int nc = 0; nc < 4; nc++) {
            __syncthreads();
            float c2v = c2g[nc * 64 + (tid & 63)];
            for (int idx = tid; idx < 4096; idx += 256) {
                int a_ = idx >> 6, b_ = idx & 63;
                float gv = G[(kb * 64 + a_) * 256 + nc * 64 + b_];
                As[b_ * 68 + a_] = c2v * gv * gv;
                Bs[b_ * 68 + a_] = W2[(mb * 64 + a_) * 256 + nc * 64 + b_];
            }
            __syncthreads();
            for (int nn = 0; nn < 64; nn++) {
                float4 av = *(const float4*)&As[nn * 68 + r0];
                float4 bv = *(const float4*)&Bs[nn * 68 + c0];
                float ar[4] = {av.x, av.y, av.z, av.w};
                float br[4] = {bv.x, bv.y, bv.z, bv.w};
                #pragma unroll
                for (int rr = 0; rr < 4; rr++)
                    #pragma unroll
                    for (int cc = 0; cc < 4; cc++)
                        a[rr][cc] = fmaf(ar[rr], br[cc], a[rr][cc]);
            }
        }
        #pragma unroll
        for (int cc = 0; cc < 4; cc++) {
            float up = 0.f;
            #pragma unroll
            for (int rr = 0; rr < 4; rr++)
                up += a[rr][cc] * c2k[r0 + rr] * W2k[(c0 + cc) * 68 + r0 + rr];
            up += __shfl_xor(up, 8, 16);
            up += __shfl_xor(up, 4, 16);
            up += __shfl_xor(up, 2, 16);
            up += __shfl_xor(up, 1, 16);
            if ((tid & 15) == 0)
                atomicAdd(&ws_f[U_F + mb * 64 + c0 + cc], up);
        }
    } else {                          // ---- T tiles: s3, s4
        int tb = b - 16, mb = tb >> 2, nb = tb & 3;
        float* As  = smem;            // P tile [ii][68] m-minor
        float* Bs  = smem + 4352;     // W1 tile [ii][68] n-minor
        float* W2s = smem + 8704;     // [mm][68]
        float* c2s = smem + 13056;    // 64
        float* c34 = smem + 13120;    // 64
        const float* P = ws_f + P_F;
        for (int idx = tid; idx < 4096; idx += 256) {
            int a_ = idx >> 6, b_ = idx & 63;
            As[b_ * 68 + a_]  = P[(mb * 64 + a_) * 64 + b_];
            Bs[b_ * 68 + a_]  = W1[(nb * 64 + a_) * 64 + b_];
            W2s[a_ * 68 + b_] = W2[(mb * 64 + a_) * 256 + nb * 64 + b_];
        }
        if (tid < 64) {
            int n = nb * 64 + tid;
            c2s[tid] = ws_f[C_F + 256 + n];
            c34[tid] = ws_f[C_F + 512 + n] * ws_f[R2_F + n];
        }
        __syncthreads();
        int m0t = (tid >> 4) * 4, n0t = (tid & 15) * 4;
        float a[4][4] = {};
        for (int ii = 0; ii < 64; ii++) {
            float4 av = *(const float4*)&As[ii * 68 + m0t];
            float4 bv = *(const float4*)&Bs[ii * 68 + n0t];
            float ar[4] = {av.x, av.y, av.z, av.w};
            float br[4] = {bv.x, bv.y, bv.z, bv.w};
            #pragma unroll
            for (int rr = 0; rr < 4; rr++)
                #pragma unroll
                for (int cc = 0; cc < 4; cc++)
                    a[rr][cc] = fmaf(ar[rr], br[cc], a[rr][cc]);
        }
        #pragma unroll
        for (int rr = 0; rr < 4; rr++) {
            float s3p = 0.f, s4p = 0.f;
            #pragma unroll
            for (int cc = 0; cc < 4; cc++) {
                float wv = W2s[(m0t + rr) * 68 + n0t + cc];
                float t  = a[rr][cc];
                s3p = fmaf(c2s[n0t + cc] * wv, t * t, s3p);
                s4p = fmaf(c34[n0t + cc] * wv, t, s4p);
            }
            s3p += __shfl_xor(s3p, 8, 16); s4p += __shfl_xor(s4p, 8, 16);
            s3p += __shfl_xor(s3p, 4, 16); s4p += __shfl_xor(s4p, 4, 16);
            s3p += __shfl_xor(s3p, 2, 16); s4p += __shfl_xor(s4p, 2, 16);
            s3p += __shfl_xor(s3p, 1, 16); s4p += __shfl_xor(s4p, 1, 16);
            if ((tid & 15) == 0) {
                atomicAdd(&ws_f[S3_F + mb * 64 + m0t + rr], s3p);
                atomicAdd(&ws_f[S4_F + mb * 64 + m0t + rr], s4p);
            }
        }
    }
    __threadfence();
    grid.sync();

    // ================= phase 3 =================
    if (b == 0) {
        int m = tid;
        float s3m = ws_f[S3_F + m], s4m = ws_f[S4_F + m];
        float p2 = ws_f[P2_F + m],  q  = ws_f[Q_F + m];
        float um = ws_f[U_F + m],   s5 = ws_f[S5_F + m];
        const float* E = ws_f + E_F;
        float y = E[768 + m] * p2 * p2
                + E[512 + m] * (2.f * q * p2 + 4.f * s3m)
                + E[256 + m] * (q * q + 2.f * um + 4.f * s4m)
                + E[m] * s5;
        double part = (double)y;
        for (int off = 32; off > 0; off >>= 1) part += __shfl_down(part, off, 64);
        if ((tid & 63) == 0) dsum[tid >> 6] = part;
        __syncthreads();
        if (tid == 0) out[0] = (float)(dsum[0] + dsum[1] + dsum[2] + dsum[3]);
    }
}

// ---------------------------------------------------------------------------
extern "C" void kernel_launch(void* const* d_in, const int* in_sizes, int n_in,
                              void* d_out, int out_size, void* d_ws, size_t ws_size,
                              hipStream_t stream) {
    const float* x  = (const float*)d_in[0];
    const float* W1 = (const float*)d_in[1];
    const float* b1 = (const float*)d_in[2];
    const float* W2 = (const float*)d_in[3];
    const float* b2 = (const float*)d_in[4];
    const float* W3 = (const float*)d_in[5];
    // b3 does not affect the 4th derivative

    float* ws_f = (float*)((char*)d_ws + 16);
    float* out  = (float*)d_out;

    void* args[] = {(void*)&x, (void*)&W1, (void*)&b1, (void*)&W2,
                    (void*)&b2, (void*)&W3, (void*)&ws_f, (void*)&out};
    hipLaunchCooperativeKernel((const void*)fused_kernel, dim3(32), dim3(256),
                               args, 0, stream);
}

// Round 9
// 117.792 us; speedup vs baseline: 1.2168x; 1.2168x over previous
//
#include <hip/hip_runtime.h>
#include <hip/hip_bf16.h>

// ---------------------------------------------------------------------------
// Closed-form bilaplacian of f(x) = W3 tanh(W2 tanh(W1 x + b1) + b2) + b3.
//   c_k[n] = phi^(k)(u0)_n ; E_k[m] = W3_m phi^(k)(v0)_m
//   A = W1 (256x64); P = W2 diag(c1) W1; G = A A^T; T = P A^T; r2 = row|A|^2
// per-m: p2=|P_m|^2; q=W2(c2 r2); s5=W2(c4 r2^2); s3=sum c2 W2 T^2;
//        s4=sum c3 r2 W2 T; u=s^T(G.*G)s, s=c2*W2row.
// Delta^2 f = sum_m E4 p2^2 + E3(2 q p2 + 4 s3) + E2(q^2 + 2u + 4 s4) + E1 s5
//
// Two kernels (boundary = the only sync; cg::grid.sync measured ~25us/sync
// on MI355X in R8 -> rejected):
//   k1 (29 blocks): Gram(0-15) | P+p2(16-23, local c1) | E/q/s5(24-27, local
//                   coefs) | c-vectors + zero ticket counter (28)
//   k2 (32 blocks): u-GEMM(0-15) | T-tiles s3/s4(16-31); partials go to
//                   write-once slots; LAST block (atomic ticket) combines.
// ---------------------------------------------------------------------------

// ws float offsets (ws_f = d_ws + 16 bytes; int ticket counter at byte 0)
#define C_F    0        // c1..c4 [4][256]
#define R2_F   1280
#define E_F    1536     // E1..E4 [4][256]
#define Q_F    2560
#define S5_F   2816
#define P2_F   3072
#define UP_F   3328     // u partials  [4 kb][256 m]
#define S3P_F  4352     // s3 partials [4 nb][256 m]
#define S4P_F  5376     // s4 partials [4 nb][256 m]
#define G_F    6400     // [256][256]
#define P_F    71936    // [256][64]

// ---------------------------------------------------------------------------
__global__ __launch_bounds__(256) void k1_kernel(
    const float* __restrict__ x,  const float* __restrict__ W1,
    const float* __restrict__ b1, const float* __restrict__ W2,
    const float* __restrict__ b2, const float* __restrict__ W3,
    float* __restrict__ ws_f, int* __restrict__ cnt) {
    __shared__ __align__(16) float smem[8704];
    int tid = threadIdx.x, b = blockIdx.x;

    if (b < 16) {                     // ---- Gram tiles G = W1 W1^T
        int nb = b >> 2, pb = b & 3;
        float* As = smem;
        float* Bs = smem + 4352;
        for (int idx = tid; idx < 4096; idx += 256) {
            int r = idx >> 6, i = idx & 63;
            As[i * 68 + r] = W1[(nb * 64 + r) * 64 + i];
            Bs[i * 68 + r] = W1[(pb * 64 + r) * 64 + i];
        }
        __syncthreads();
        int r0 = (tid & 15) * 4, c0 = (tid >> 4) * 4;
        float a[4][4] = {};
        for (int i = 0; i < 64; i++) {
            float4 av = *(const float4*)&As[i * 68 + r0];
            float4 bv = *(const float4*)&Bs[i * 68 + c0];
            float ar[4] = {av.x, av.y, av.z, av.w};
            float br[4] = {bv.x, bv.y, bv.z, bv.w};
            #pragma unroll
            for (int rr = 0; rr < 4; rr++)
                #pragma unroll
                for (int cc = 0; cc < 4; cc++)
                    a[rr][cc] = fmaf(ar[rr], br[cc], a[rr][cc]);
        }
        float* G = ws_f + G_F;
        #pragma unroll
        for (int rr = 0; rr < 4; rr++)
            #pragma unroll
            for (int cc = 0; cc < 4; cc++)
                G[(nb * 64 + r0 + rr) * 256 + pb * 64 + c0 + cc] = a[rr][cc];
    } else if (b < 24) {              // ---- P = W2 diag(c1) W1 (+p2), local c1
        int m0 = (b - 16) * 32;
        float* Wc  = smem;            // [64n][34]
        float* Bc  = smem + 2176;     // [64n][68]
        float* c1s = smem + 6528;     // 256
        float* xs  = smem + 6784;     // 64
        if (tid < 64) xs[tid] = x[tid];
        __syncthreads();
        {
            const float4* row = (const float4*)(W1 + tid * 64);
            const float4* xv4 = (const float4*)xs;
            float u0 = b1[tid];
            #pragma unroll
            for (int k = 0; k < 16; k++) {
                float4 w = row[k], xv = xv4[k];
                u0 += w.x * xv.x + w.y * xv.y + w.z * xv.z + w.w * xv.w;
            }
            float T = tanhf(u0);
            c1s[tid] = 1.f - T * T;
        }
        float acc2[2][4] = {};
        int tm2 = (tid & 15) * 2, ti = (tid >> 4) * 4;
        for (int nc = 0; nc < 4; nc++) {
            __syncthreads();
            for (int idx = tid; idx < 2048; idx += 256) {
                int mm = idx >> 6, nn = idx & 63;
                Wc[nn * 34 + mm] = W2[(m0 + mm) * 256 + nc * 64 + nn];
            }
            for (int idx = tid; idx < 4096; idx += 256) {
                int nn = idx >> 6, ii = idx & 63, n = nc * 64 + nn;
                Bc[nn * 68 + ii] = c1s[n] * W1[n * 64 + ii];
            }
            __syncthreads();
            for (int nn = 0; nn < 64; nn++) {
                float2 a2 = *(const float2*)&Wc[nn * 34 + tm2];
                float4 b4 = *(const float4*)&Bc[nn * 68 + ti];
                float br[4] = {b4.x, b4.y, b4.z, b4.w};
                #pragma unroll
                for (int j = 0; j < 4; j++) {
                    acc2[0][j] = fmaf(a2.x, br[j], acc2[0][j]);
                    acc2[1][j] = fmaf(a2.y, br[j], acc2[1][j]);
                }
            }
        }
        float* P = ws_f + P_F;
        float s0 = 0.f, s1 = 0.f;
        #pragma unroll
        for (int j = 0; j < 4; j++) {
            P[(m0 + tm2) * 64 + ti + j]     = acc2[0][j];
            P[(m0 + tm2 + 1) * 64 + ti + j] = acc2[1][j];
            s0 += acc2[0][j] * acc2[0][j];
            s1 += acc2[1][j] * acc2[1][j];
        }
        __syncthreads();
        float* red = smem;            // [32][16]
        red[tm2 * 16 + (tid >> 4)]       = s0;
        red[(tm2 + 1) * 16 + (tid >> 4)] = s1;
        __syncthreads();
        if (tid < 32) {
            float p = 0.f;
            #pragma unroll
            for (int g = 0; g < 16; g++) p += red[tid * 16 + g];
            ws_f[P2_F + m0 + tid] = p;
        }
    } else if (b < 28) {              // ---- E, q, s5 (local coefs)
        int m0 = (b - 24) * 64;
        float* Ws   = smem;           // [64n][65]
        float* h0s  = smem + 4160;
        float* aqs  = smem + 4416;
        float* a5s  = smem + 4672;
        float* part = smem + 4928;    // [3][256]
        float* xs   = smem + 5696;    // 64
        if (tid < 64) xs[tid] = x[tid];
        __syncthreads();
        {
            const float4* row = (const float4*)(W1 + tid * 64);
            const float4* xv4 = (const float4*)xs;
            float u0 = b1[tid], r2v = 0.f;
            #pragma unroll
            for (int k = 0; k < 16; k++) {
                float4 w = row[k], xv = xv4[k];
                u0  += w.x * xv.x + w.y * xv.y + w.z * xv.z + w.w * xv.w;
                r2v += w.x * w.x + w.y * w.y + w.z * w.z + w.w * w.w;
            }
            float T = tanhf(u0), s = 1.f - T * T;
            float c2 = -2.f * T * s;
            float c4 = s * T * (16.f - 24.f * T * T);
            h0s[tid] = T;
            aqs[tid] = c2 * r2v;
            a5s[tid] = c4 * r2v * r2v;
        }
        int mm = tid & 63, nq = tid >> 6;
        float pv = 0.f, pq = 0.f, p5 = 0.f;
        for (int nc = 0; nc < 4; nc++) {
            __syncthreads();
            for (int idx = tid; idx < 4096; idx += 256) {
                int m2 = idx >> 6, nn = idx & 63;
                Ws[nn * 65 + m2] = W2[(m0 + m2) * 256 + nc * 64 + nn];
            }
            __syncthreads();
            #pragma unroll
            for (int k = 0; k < 16; k++) {
                int nn = nq * 16 + k, n = nc * 64 + nn;
                float wv = Ws[nn * 65 + mm];
                pv = fmaf(wv, h0s[n], pv);
                pq = fmaf(wv, aqs[n], pq);
                p5 = fmaf(wv, a5s[n], p5);
            }
        }
        part[nq * 64 + mm]       = pv;
        part[256 + nq * 64 + mm] = pq;
        part[512 + nq * 64 + mm] = p5;
        __syncthreads();
        if (tid < 64) {
            int m = m0 + tid;
            float v  = b2[m] + part[tid] + part[64 + tid] + part[128 + tid] + part[192 + tid];
            float q  = part[256 + tid] + part[320 + tid] + part[384 + tid] + part[448 + tid];
            float s5 = part[512 + tid] + part[576 + tid] + part[640 + tid] + part[704 + tid];
            float T2 = tanhf(v), s2 = 1.f - T2 * T2, w3 = W3[m];
            float* E = ws_f + E_F;
            E[m]       = w3 * s2;
            E[256 + m] = -2.f * w3 * T2 * s2;
            E[512 + m] = w3 * s2 * (6.f * T2 * T2 - 2.f);
            E[768 + m] = w3 * s2 * T2 * (16.f - 24.f * T2 * T2);
            ws_f[Q_F + m]  = q;
            ws_f[S5_F + m] = s5;
        }
    } else {                          // ---- c-vectors + zero ticket counter
        float* xs = smem;
        if (tid < 64) xs[tid] = x[tid];
        __syncthreads();
        const float4* row = (const float4*)(W1 + tid * 64);
        const float4* xv4 = (const float4*)xs;
        float u0 = b1[tid], r2v = 0.f;
        #pragma unroll
        for (int k = 0; k < 16; k++) {
            float4 w = row[k], xv = xv4[k];
            u0  += w.x * xv.x + w.y * xv.y + w.z * xv.z + w.w * xv.w;
            r2v += w.x * w.x + w.y * w.y + w.z * w.z + w.w * w.w;
        }
        float T = tanhf(u0), s = 1.f - T * T;
        ws_f[C_F + tid]       = s;
        ws_f[C_F + 256 + tid] = -2.f * T * s;
        ws_f[C_F + 512 + tid] = s * (6.f * T * T - 2.f);
        ws_f[C_F + 768 + tid] = s * T * (16.f - 24.f * T * T);
        ws_f[R2_F + tid] = r2v;
        if (tid == 0) *cnt = 0;
    }
}

// ---------------------------------------------------------------------------
// k2: u-GEMM (0-15) | T-tiles (16-31); write-once partial slots; last block
//     (atomic ticket) combines and writes out. No grid sync, no spinning.
// ---------------------------------------------------------------------------
__global__ __launch_bounds__(256) void k2_kernel(
    const float* __restrict__ W1, const float* __restrict__ W2,
    float* __restrict__ ws_f, int* __restrict__ cnt, float* __restrict__ out) {
    __shared__ __align__(16) float smem[13248];
    __shared__ int lastFlag;
    __shared__ double dsum[4];
    int tid = threadIdx.x, b = blockIdx.x;

    if (b < 16) {                     // ---- u-GEMM: Yt=(G.*G diag(c2))W2^T
        int kb = b >> 2, mb = b & 3;
        const float* c2g = ws_f + C_F + 256;
        float* As  = smem;            // [nn][68]
        float* Bs  = smem + 4352;     // [nn][68]
        float* W2k = smem + 8704;     // [mm][68]
        float* c2k = smem + 13056;    // 64
        for (int idx = tid; idx < 4096; idx += 256) {
            int a_ = idx >> 6, b_ = idx & 63;
            W2k[a_ * 68 + b_] = W2[(mb * 64 + a_) * 256 + kb * 64 + b_];
        }
        if (tid < 64) c2k[tid] = c2g[kb * 64 + tid];
        int r0 = (tid & 15) * 4, c0 = (tid >> 4) * 4;
        float a[4][4] = {};
        const float* G = ws_f + G_F;
        for (int nc = 0; nc < 4; nc++) {
            __syncthreads();
            float c2v = c2g[nc * 64 + (tid & 63)];
            for (int idx = tid; idx < 4096; idx += 256) {
                int a_ = idx >> 6, b_ = idx & 63;
                float gv = G[(kb * 64 + a_) * 256 + nc * 64 + b_];
                As[b_ * 68 + a_] = c2v * gv * gv;
                Bs[b_ * 68 + a_] = W2[(mb * 64 + a_) * 256 + nc * 64 + b_];
            }
            __syncthreads();
            for (int nn = 0; nn < 64; nn++) {
                float4 av = *(const float4*)&As[nn * 68 + r0];
                float4 bv = *(const float4*)&Bs[nn * 68 + c0];
                float ar[4] = {av.x, av.y, av.z, av.w};
                float br[4] = {bv.x, bv.y, bv.z, bv.w};
                #pragma unroll
                for (int rr = 0; rr < 4; rr++)
                    #pragma unroll
                    for (int cc = 0; cc < 4; cc++)
                        a[rr][cc] = fmaf(ar[rr], br[cc], a[rr][cc]);
            }
        }
        #pragma unroll
        for (int cc = 0; cc < 4; cc++) {
            float up = 0.f;
            #pragma unroll
            for (int rr = 0; rr < 4; rr++)
                up += a[rr][cc] * c2k[r0 + rr] * W2k[(c0 + cc) * 68 + r0 + rr];
            up += __shfl_xor(up, 8, 16);
            up += __shfl_xor(up, 4, 16);
            up += __shfl_xor(up, 2, 16);
            up += __shfl_xor(up, 1, 16);
            if ((tid & 15) == 0)
                ws_f[UP_F + kb * 256 + mb * 64 + c0 + cc] = up;   // write-once
        }
    } else {                          // ---- T tiles: s3, s4 partials
        int tb = b - 16, mb = tb >> 2, nb = tb & 3;
        float* As  = smem;            // P tile [ii][68] m-minor
        float* Bs  = smem + 4352;     // W1 tile [ii][68] n-minor
        float* W2s = smem + 8704;     // [mm][68]
        float* c2s = smem + 13056;    // 64
        float* c34 = smem + 13120;    // 64
        const float* P = ws_f + P_F;
        for (int idx = tid; idx < 4096; idx += 256) {
            int a_ = idx >> 6, b_ = idx & 63;
            As[b_ * 68 + a_]  = P[(mb * 64 + a_) * 64 + b_];
            Bs[b_ * 68 + a_]  = W1[(nb * 64 + a_) * 64 + b_];
            W2s[a_ * 68 + b_] = W2[(mb * 64 + a_) * 256 + nb * 64 + b_];
        }
        if (tid < 64) {
            int n = nb * 64 + tid;
            c2s[tid] = ws_f[C_F + 256 + n];
            c34[tid] = ws_f[C_F + 512 + n] * ws_f[R2_F + n];
        }
        __syncthreads();
        int m0t = (tid >> 4) * 4, n0t = (tid & 15) * 4;
        float a[4][4] = {};
        for (int ii = 0; ii < 64; ii++) {
            float4 av = *(const float4*)&As[ii * 68 + m0t];
            float4 bv = *(const float4*)&Bs[ii * 68 + n0t];
            float ar[4] = {av.x, av.y, av.z, av.w};
            float br[4] = {bv.x, bv.y, bv.z, bv.w};
            #pragma unroll
            for (int rr = 0; rr < 4; rr++)
                #pragma unroll
                for (int cc = 0; cc < 4; cc++)
                    a[rr][cc] = fmaf(ar[rr], br[cc], a[rr][cc]);
        }
        #pragma unroll
        for (int rr = 0; rr < 4; rr++) {
            float s3p = 0.f, s4p = 0.f;
            #pragma unroll
            for (int cc = 0; cc < 4; cc++) {
                float wv = W2s[(m0t + rr) * 68 + n0t + cc];
                float t  = a[rr][cc];
                s3p = fmaf(c2s[n0t + cc] * wv, t * t, s3p);
                s4p = fmaf(c34[n0t + cc] * wv, t, s4p);
            }
            s3p += __shfl_xor(s3p, 8, 16); s4p += __shfl_xor(s4p, 8, 16);
            s3p += __shfl_xor(s3p, 4, 16); s4p += __shfl_xor(s4p, 4, 16);
            s3p += __shfl_xor(s3p, 2, 16); s4p += __shfl_xor(s4p, 2, 16);
            s3p += __shfl_xor(s3p, 1, 16); s4p += __shfl_xor(s4p, 1, 16);
            if ((tid & 15) == 0) {
                ws_f[S3P_F + nb * 256 + mb * 64 + m0t + rr] = s3p;  // write-once
                ws_f[S4P_F + nb * 256 + mb * 64 + m0t + rr] = s4p;  // write-once
            }
        }
    }

    // ---- ticket: last-arriving block combines (no waiting, no co-residency)
    __threadfence();
    if (tid == 0) lastFlag = (atomicAdd(cnt, 1) == 31) ? 1 : 0;
    __syncthreads();
    if (lastFlag) {
        __threadfence();
        volatile float* wsv = ws_f;
        int m = tid;
        float um  = wsv[UP_F  + m] + wsv[UP_F  + 256 + m] + wsv[UP_F  + 512 + m] + wsv[UP_F  + 768 + m];
        float s3m = wsv[S3P_F + m] + wsv[S3P_F + 256 + m] + wsv[S3P_F + 512 + m] + wsv[S3P_F + 768 + m];
        float s4m = wsv[S4P_F + m] + wsv[S4P_F + 256 + m] + wsv[S4P_F + 512 + m] + wsv[S4P_F + 768 + m];
        float p2 = wsv[P2_F + m], q = wsv[Q_F + m], s5 = wsv[S5_F + m];
        float E1 = wsv[E_F + m], E2 = wsv[E_F + 256 + m];
        float E3 = wsv[E_F + 512 + m], E4 = wsv[E_F + 768 + m];
        float y = E4 * p2 * p2
                + E3 * (2.f * q * p2 + 4.f * s3m)
                + E2 * (q * q + 2.f * um + 4.f * s4m)
                + E1 * s5;
        double part = (double)y;
        for (int off = 32; off > 0; off >>= 1) part += __shfl_down(part, off, 64);
        if ((tid & 63) == 0) dsum[tid >> 6] = part;
        __syncthreads();
        if (tid == 0) out[0] = (float)(dsum[0] + dsum[1] + dsum[2] + dsum[3]);
    }
}

// ---------------------------------------------------------------------------
extern "C" void kernel_launch(void* const* d_in, const int* in_sizes, int n_in,
                              void* d_out, int out_size, void* d_ws, size_t ws_size,
                              hipStream_t stream) {
    const float* x  = (const float*)d_in[0];
    const float* W1 = (const float*)d_in[1];
    const float* b1 = (const float*)d_in[2];
    const float* W2 = (const float*)d_in[3];
    const float* b2 = (const float*)d_in[4];
    const float* W3 = (const float*)d_in[5];
    // b3 does not affect the 4th derivative

    char*  ws   = (char*)d_ws;
    int*   cnt  = (int*)ws;
    float* ws_f = (float*)(ws + 16);
    float* out  = (float*)d_out;

    k1_kernel<<<29, 256, 0, stream>>>(x, W1, b1, W2, b2, W3, ws_f, cnt);
    k2_kernel<<<32, 256, 0, stream>>>(W1, W2, ws_f, cnt, out);
}

// Round 10
// 108.306 us; speedup vs baseline: 1.3234x; 1.0876x over previous
//
#include <hip/hip_runtime.h>
#include <hip/hip_bf16.h>

// ---------------------------------------------------------------------------
// Closed-form bilaplacian of f(x) = W3 tanh(W2 tanh(W1 x + b1) + b2) + b3.
//   c_k[n] = phi^(k)(u0)_n ; E_k[m] = W3_m phi^(k)(v0)_m
//   A = W1 (256x64); P = W2 diag(c1) W1; G = A A^T; T = P A^T; r2 = row|A|^2
// per-m: p2=|P_m|^2; q=W2(c2 r2); s5=W2(c4 r2^2); s3=sum c2 W2 T^2;
//        s4=sum c3 r2 W2 T; u=s^T(G.*G)s, s=c2*W2row.
// Delta^2 f = sum_m E4 p2^2 + E3(2 q p2 + 4 s3) + E2(q^2 + 2u + 4 s4) + E1 s5
//
// SINGLE kernel, 36 independent blocks (no cross-block data deps):
//   0-15  u-tiles (kb,mb): local c2 + local G-row-slice Gram, then
//         Yt=(G.*G diag(c2))W2^T tile, u-partial -> write-once UP slot
//   16-31 T-tiles (mb,nb): local c1/c2/c3*r2 + local P-row-slice, then
//         T=P A^T tile, s3/s4 partials -> write-once slots (nb==0: also p2)
//   32-35 E/q/s5 (local coefs)
//   last-arriving block (atomic ticket, zeroed by pre-launch memset)
//   combines -> out.  (R8 measured cg::grid.sync ~25us/sync -> rejected;
//   kernel-boundary sync also rejected: slice recompute is ~1.7us.)
// ---------------------------------------------------------------------------

// ws float offsets (ws_f = d_ws + 16 bytes; int ticket counter at byte 0)
#define E_F    0        // E1..E4 [4][256]
#define Q_F    1024
#define S5_F   1280
#define P2_F   1536
#define UP_F   1792     // u partials  [4 kb][256 m]
#define S3P_F  2816     // s3 partials [4 nb][256 m]
#define S4P_F  3840     // s4 partials [4 nb][256 m]

__global__ __launch_bounds__(256) void fused_kernel(
    const float* __restrict__ x,  const float* __restrict__ W1,
    const float* __restrict__ b1, const float* __restrict__ W2,
    const float* __restrict__ b2, const float* __restrict__ W3,
    float* __restrict__ ws_f, int* __restrict__ cnt, float* __restrict__ out) {
    __shared__ __align__(16) float smem[13888];
    __shared__ int lastFlag;
    __shared__ double dsum[4];
    int tid = threadIdx.x, b = blockIdx.x;

    if (b < 16) {              // ======== u-tile (kb,mb), fully local ========
        int kb = b >> 2, mb = b & 3;
        float* As  = smem;            // [i][68] rows of A[kb] (i-minor=col idx)
        float* Bs  = smem + 4352;     // A-chunk / W2-chunk / W2k
        float* Cs  = smem + 8704;     // As2 = c2[n]*G[k][n]^2, [n][68] k-minor
        float* c2s = smem + 13056;    // 256
        float* xs  = smem + 13312;    // 64
        if (tid < 64) xs[tid] = x[tid];
        __syncthreads();
        {   // c2 for all 256 rows (one row per thread)
            const float4* row = (const float4*)(W1 + tid * 64);
            const float4* xv4 = (const float4*)xs;
            float u0 = b1[tid];
            #pragma unroll
            for (int k = 0; k < 16; k++) {
                float4 w = row[k], xv = xv4[k];
                u0 += w.x * xv.x + w.y * xv.y + w.z * xv.z + w.w * xv.w;
            }
            float T = tanhf(u0), s = 1.f - T * T;
            c2s[tid] = -2.f * T * s;
        }
        for (int idx = tid; idx < 4096; idx += 256) {   // stage A[kb] rows
            int r = idx >> 6, i = idx & 63;
            As[i * 68 + r] = W1[(kb * 64 + r) * 64 + i];
        }
        __syncthreads();
        int r0 = (tid & 15) * 4, c0 = (tid >> 4) * 4;   // r0: k, c0: n (then m)
        float acc[4][4] = {};
        for (int nc = 0; nc < 4; nc++) {
            for (int idx = tid; idx < 4096; idx += 256) {  // A[nc] rows
                int r = idx >> 6, i = idx & 63;
                Bs[i * 68 + r] = W1[(nc * 64 + r) * 64 + i];
            }
            __syncthreads();
            float g[4][4] = {};
            for (int i = 0; i < 64; i++) {               // Gram tile
                float4 av = *(const float4*)&As[i * 68 + r0];
                float4 bv = *(const float4*)&Bs[i * 68 + c0];
                float ar[4] = {av.x, av.y, av.z, av.w};
                float br[4] = {bv.x, bv.y, bv.z, bv.w};
                #pragma unroll
                for (int rr = 0; rr < 4; rr++)
                    #pragma unroll
                    for (int cc = 0; cc < 4; cc++)
                        g[rr][cc] = fmaf(ar[rr], br[cc], g[rr][cc]);
            }
            #pragma unroll
            for (int rr = 0; rr < 4; rr++)
                #pragma unroll
                for (int cc = 0; cc < 4; cc++) {
                    float gv = g[rr][cc];
                    Cs[(c0 + cc) * 68 + r0 + rr] = c2s[nc * 64 + c0 + cc] * gv * gv;
                }
            __syncthreads();                             // Cs ready, Bs free
            for (int idx = tid; idx < 4096; idx += 256) {  // W2 chunk [n][m]
                int a_ = idx >> 6, b_ = idx & 63;        // a_=m, b_=n
                Bs[b_ * 68 + a_] = W2[(mb * 64 + a_) * 256 + nc * 64 + b_];
            }
            __syncthreads();
            for (int nn = 0; nn < 64; nn++) {            // acc[k][m] += ...
                float4 av = *(const float4*)&Cs[nn * 68 + r0];
                float4 bv = *(const float4*)&Bs[nn * 68 + c0];
                float ar[4] = {av.x, av.y, av.z, av.w};
                float br[4] = {bv.x, bv.y, bv.z, bv.w};
                #pragma unroll
                for (int rr = 0; rr < 4; rr++)
                    #pragma unroll
                    for (int cc = 0; cc < 4; cc++)
                        acc[rr][cc] = fmaf(ar[rr], br[cc], acc[rr][cc]);
            }
            __syncthreads();                             // done with Bs/Cs
        }
        for (int idx = tid; idx < 4096; idx += 256) {    // W2k [m][68 k]
            int a_ = idx >> 6, b_ = idx & 63;            // a_=m, b_=k
            Bs[a_ * 68 + b_] = W2[(mb * 64 + a_) * 256 + kb * 64 + b_];
        }
        __syncthreads();
        #pragma unroll
        for (int cc = 0; cc < 4; cc++) {                 // u partial per m
            float up = 0.f;
            #pragma unroll
            for (int rr = 0; rr < 4; rr++)
                up += acc[rr][cc] * c2s[kb * 64 + r0 + rr] * Bs[(c0 + cc) * 68 + r0 + rr];
            up += __shfl_xor(up, 8, 16);
            up += __shfl_xor(up, 4, 16);
            up += __shfl_xor(up, 2, 16);
            up += __shfl_xor(up, 1, 16);
            if ((tid & 15) == 0)
                ws_f[UP_F + kb * 256 + mb * 64 + c0 + cc] = up;   // write-once
        }
    } else if (b < 32) {       // ======== T-tile (mb,nb), fully local ========
        int tb = b - 16, mb = tb >> 2, nb = tb & 3;
        float* As   = smem;           // Wp [n][m-minor] then W1t [ii][n-minor]
        float* Bs2  = smem + 4352;    // Bp [n][i-minor]  then W2s [m][n]
        float* Pt   = smem + 8704;    // P tile [ii][68] m-minor
        float* c1s  = smem + 13056;   // 256
        float* c2v  = smem + 13312;   // 256
        float* c34v = smem + 13568;   // 256: c3*r2
        float* xs   = smem + 13824;   // 64
        if (tid < 64) xs[tid] = x[tid];
        __syncthreads();
        {   // c1, c2, c3*r2 for all 256 rows
            const float4* row = (const float4*)(W1 + tid * 64);
            const float4* xv4 = (const float4*)xs;
            float u0 = b1[tid], r2v = 0.f;
            #pragma unroll
            for (int k = 0; k < 16; k++) {
                float4 w = row[k], xv = xv4[k];
                u0  += w.x * xv.x + w.y * xv.y + w.z * xv.z + w.w * xv.w;
                r2v += w.x * w.x + w.y * w.y + w.z * w.z + w.w * w.w;
            }
            float T = tanhf(u0), s = 1.f - T * T;
            c1s[tid]  = s;
            c2v[tid]  = -2.f * T * s;
            c34v[tid] = s * (6.f * T * T - 2.f) * r2v;
        }
        __syncthreads();
        int r0p = (tid >> 4) * 4, c0p = (tid & 15) * 4;  // r0p: m, c0p: i
        float acc[4][4] = {};
        for (int nc = 0; nc < 4; nc++) {                 // P = W2 diag(c1) W1
            for (int idx = tid; idx < 4096; idx += 256) { // Wp [n][m-minor]
                int a_ = idx >> 6, b_ = idx & 63;        // a_=m, b_=n
                As[b_ * 68 + a_] = W2[(mb * 64 + a_) * 256 + nc * 64 + b_];
            }
            for (int idx = tid; idx < 4096; idx += 256) { // Bp [n][i-minor]
                int a_ = idx >> 6, b_ = idx & 63;        // a_=n, b_=i
                Bs2[a_ * 68 + b_] = c1s[nc * 64 + a_] * W1[(nc * 64 + a_) * 64 + b_];
            }
            __syncthreads();
            for (int nn = 0; nn < 64; nn++) {
                float4 av = *(const float4*)&As[nn * 68 + r0p];
                float4 bv = *(const float4*)&Bs2[nn * 68 + c0p];
                float ar[4] = {av.x, av.y, av.z, av.w};
                float br[4] = {bv.x, bv.y, bv.z, bv.w};
                #pragma unroll
                for (int rr = 0; rr < 4; rr++)
                    #pragma unroll
                    for (int cc = 0; cc < 4; cc++)
                        acc[rr][cc] = fmaf(ar[rr], br[cc], acc[rr][cc]);
            }
            __syncthreads();
        }
        if (nb == 0) {                                   // p2 per m (once)
            #pragma unroll
            for (int rr = 0; rr < 4; rr++) {
                float p = 0.f;
                #pragma unroll
                for (int cc = 0; cc < 4; cc++) p += acc[rr][cc] * acc[rr][cc];
                p += __shfl_xor(p, 8, 16);
                p += __shfl_xor(p, 4, 16);
                p += __shfl_xor(p, 2, 16);
                p += __shfl_xor(p, 1, 16);
                if ((tid & 15) == 0)
                    ws_f[P2_F + mb * 64 + r0p + rr] = p;          // write-once
            }
        }
        #pragma unroll
        for (int rr = 0; rr < 4; rr++)                   // Pt [i][m-minor]
            #pragma unroll
            for (int cc = 0; cc < 4; cc++)
                Pt[(c0p + cc) * 68 + r0p + rr] = acc[rr][cc];
        __syncthreads();
        for (int idx = tid; idx < 4096; idx += 256) {    // W1t [ii][n-minor]
            int a_ = idx >> 6, b_ = idx & 63;            // a_=n, b_=ii
            As[b_ * 68 + a_] = W1[(nb * 64 + a_) * 64 + b_];
        }
        for (int idx = tid; idx < 4096; idx += 256) {    // W2s [m][68 n]
            int a_ = idx >> 6, b_ = idx & 63;            // a_=m, b_=n
            Bs2[a_ * 68 + b_] = W2[(mb * 64 + a_) * 256 + nb * 64 + b_];
        }
        __syncthreads();
        int m0t = (tid >> 4) * 4, n0t = (tid & 15) * 4;
        float t4[4][4] = {};
        for (int ii = 0; ii < 64; ii++) {                // T tile
            float4 av = *(const float4*)&Pt[ii * 68 + m0t];
            float4 bv = *(const float4*)&As[ii * 68 + n0t];
            float ar[4] = {av.x, av.y, av.z, av.w};
            float br[4] = {bv.x, bv.y, bv.z, bv.w};
            #pragma unroll
            for (int rr = 0; rr < 4; rr++)
                #pragma unroll
                for (int cc = 0; cc < 4; cc++)
                    t4[rr][cc] = fmaf(ar[rr], br[cc], t4[rr][cc]);
        }
        #pragma unroll
        for (int rr = 0; rr < 4; rr++) {                 // s3/s4 partials
            float s3p = 0.f, s4p = 0.f;
            #pragma unroll
            for (int cc = 0; cc < 4; cc++) {
                float wv = Bs2[(m0t + rr) * 68 + n0t + cc];
                float t  = t4[rr][cc];
                s3p = fmaf(c2v[nb * 64 + n0t + cc] * wv, t * t, s3p);
                s4p = fmaf(c34v[nb * 64 + n0t + cc] * wv, t, s4p);
            }
            s3p += __shfl_xor(s3p, 8, 16); s4p += __shfl_xor(s4p, 8, 16);
            s3p += __shfl_xor(s3p, 4, 16); s4p += __shfl_xor(s4p, 4, 16);
            s3p += __shfl_xor(s3p, 2, 16); s4p += __shfl_xor(s4p, 2, 16);
            s3p += __shfl_xor(s3p, 1, 16); s4p += __shfl_xor(s4p, 1, 16);
            if ((tid & 15) == 0) {
                ws_f[S3P_F + nb * 256 + mb * 64 + m0t + rr] = s3p;  // write-once
                ws_f[S4P_F + nb * 256 + mb * 64 + m0t + rr] = s4p;  // write-once
            }
        }
    } else {                   // ======== E, q, s5 (local coefs) ========
        int m0 = (b - 32) * 64;
        float* Ws   = smem;           // [64n][65]
        float* h0s  = smem + 4160;
        float* aqs  = smem + 4416;
        float* a5s  = smem + 4672;
        float* part = smem + 4928;    // [3][256]
        float* xs   = smem + 5696;    // 64
        if (tid < 64) xs[tid] = x[tid];
        __syncthreads();
        {
            const float4* row = (const float4*)(W1 + tid * 64);
            const float4* xv4 = (const float4*)xs;
            float u0 = b1[tid], r2v = 0.f;
            #pragma unroll
            for (int k = 0; k < 16; k++) {
                float4 w = row[k], xv = xv4[k];
                u0  += w.x * xv.x + w.y * xv.y + w.z * xv.z + w.w * xv.w;
                r2v += w.x * w.x + w.y * w.y + w.z * w.z + w.w * w.w;
            }
            float T = tanhf(u0), s = 1.f - T * T;
            float c2 = -2.f * T * s;
            float c4 = s * T * (16.f - 24.f * T * T);
            h0s[tid] = T;
            aqs[tid] = c2 * r2v;
            a5s[tid] = c4 * r2v * r2v;
        }
        int mm = tid & 63, nq = tid >> 6;
        float pv = 0.f, pq = 0.f, p5 = 0.f;
        for (int nc = 0; nc < 4; nc++) {
            __syncthreads();
            for (int idx = tid; idx < 4096; idx += 256) {
                int m2 = idx >> 6, nn = idx & 63;
                Ws[nn * 65 + m2] = W2[(m0 + m2) * 256 + nc * 64 + nn];
            }
            __syncthreads();
            #pragma unroll
            for (int k = 0; k < 16; k++) {
                int nn = nq * 16 + k, n = nc * 64 + nn;
                float wv = Ws[nn * 65 + mm];
                pv = fmaf(wv, h0s[n], pv);
                pq = fmaf(wv, aqs[n], pq);
                p5 = fmaf(wv, a5s[n], p5);
            }
        }
        part[nq * 64 + mm]       = pv;
        part[256 + nq * 64 + mm] = pq;
        part[512 + nq * 64 + mm] = p5;
        __syncthreads();
        if (tid < 64) {
            int m = m0 + tid;
            float v  = b2[m] + part[tid] + part[64 + tid] + part[128 + tid] + part[192 + tid];
            float q  = part[256 + tid] + part[320 + tid] + part[384 + tid] + part[448 + tid];
            float s5 = part[512 + tid] + part[576 + tid] + part[640 + tid] + part[704 + tid];
            float T2 = tanhf(v), s2 = 1.f - T2 * T2, w3 = W3[m];
            ws_f[E_F + m]       = w3 * s2;
            ws_f[E_F + 256 + m] = -2.f * w3 * T2 * s2;
            ws_f[E_F + 512 + m] = w3 * s2 * (6.f * T2 * T2 - 2.f);
            ws_f[E_F + 768 + m] = w3 * s2 * T2 * (16.f - 24.f * T2 * T2);
            ws_f[Q_F + m]  = q;
            ws_f[S5_F + m] = s5;
        }
    }

    // ---- ticket: last-arriving block combines (no waiting, no co-residency)
    __threadfence();
    if (tid == 0) lastFlag = (atomicAdd(cnt, 1) == 35) ? 1 : 0;
    __syncthreads();
    if (lastFlag) {
        __threadfence();
        volatile float* wsv = ws_f;
        int m = tid;
        float um  = wsv[UP_F  + m] + wsv[UP_F  + 256 + m] + wsv[UP_F  + 512 + m] + wsv[UP_F  + 768 + m];
        float s3m = wsv[S3P_F + m] + wsv[S3P_F + 256 + m] + wsv[S3P_F + 512 + m] + wsv[S3P_F + 768 + m];
        float s4m = wsv[S4P_F + m] + wsv[S4P_F + 256 + m] + wsv[S4P_F + 512 + m] + wsv[S4P_F + 768 + m];
        float p2 = wsv[P2_F + m], q = wsv[Q_F + m], s5 = wsv[S5_F + m];
        float E1 = wsv[E_F + m], E2 = wsv[E_F + 256 + m];
        float E3 = wsv[E_F + 512 + m], E4 = wsv[E_F + 768 + m];
        float y = E4 * p2 * p2
                + E3 * (2.f * q * p2 + 4.f * s3m)
                + E2 * (q * q + 2.f * um + 4.f * s4m)
                + E1 * s5;
        double part = (double)y;
        for (int off = 32; off > 0; off >>= 1) part += __shfl_down(part, off, 64);
        if ((tid & 63) == 0) dsum[tid >> 6] = part;
        __syncthreads();
        if (tid == 0) out[0] = (float)(dsum[0] + dsum[1] + dsum[2] + dsum[3]);
    }
}

// ---------------------------------------------------------------------------
extern "C" void kernel_launch(void* const* d_in, const int* in_sizes, int n_in,
                              void* d_out, int out_size, void* d_ws, size_t ws_size,
                              hipStream_t stream) {
    const float* x  = (const float*)d_in[0];
    const float* W1 = (const float*)d_in[1];
    const float* b1 = (const float*)d_in[2];
    const float* W2 = (const float*)d_in[3];
    const float* b2 = (const float*)d_in[4];
    const float* W3 = (const float*)d_in[5];
    // b3 does not affect the 4th derivative

    char*  ws   = (char*)d_ws;
    int*   cnt  = (int*)ws;
    float* ws_f = (float*)(ws + 16);
    float* out  = (float*)d_out;

    hipMemsetAsync(ws, 0, 16, stream);   // zero the ticket counter (capturable)
    fused_kernel<<<36, 256, 0, stream>>>(x, W1, b1, W2, b2, W3, ws_f, cnt, out);
}

// Round 11
// 108.189 us; speedup vs baseline: 1.3249x; 1.0011x over previous
//
#include <hip/hip_runtime.h>
#include <hip/hip_bf16.h>

// ---------------------------------------------------------------------------
// Closed-form bilaplacian of f(x) = W3 tanh(W2 tanh(W1 x + b1) + b2) + b3.
//   c_k[n] = phi^(k)(u0)_n ; E_k[m] = W3_m phi^(k)(v0)_m
//   A = W1 (256x64); P = W2 diag(c1) W1; G = A A^T; T = P A^T; r2 = row|A|^2
// per-m: p2=|P_m|^2; q=W2(c2 r2); s5=W2(c4 r2^2); s3=sum c2 W2 T^2;
//        s4=sum c3 r2 W2 T; u=s^T(G.*G)s, s=c2*W2row.
// Delta^2 f = sum_m E4 p2^2 + E3(2 q p2 + 4 s3) + E2(q^2 + 2u + 4 s4) + E1 s5
//
// R10 lesson: one block/CU + serial chain of 8 tile-matmuls = latency-bound
// 45us (VALUBusy 2.3%). Fix: every block does AT MOST ONE 64^3 tile matmul;
// K-chunks (nc) are split across blocks with write-once partial slots; the
// single producer->consumer sync is the k1|k2 kernel boundary (~2-4us).
//   k1 (53): Gram(0-15) | P-partials(16-47: mb x nc) | E/q/s5(48-51) | coef(52)
//   k2 (80): u-tiles(0-63: kb,mb,nc) | T-tiles(64-79: mb,nb; nb==0 also p2)
//            + last-arriving-block ticket combine (cnt zeroed by k1 coef).
// ---------------------------------------------------------------------------

// ws float offsets (ws_f = d_ws + 16 bytes; int ticket counter at byte 0)
#define E_F    0        // E1..E4 [4][256]
#define Q_F    1024
#define S5_F   1280
#define P2_F   1536
#define CV_F   1792     // c2 [256], then c3*r2 [256]
#define UP_F   2304     // u partials  [16 (kb,nc)][256 m]
#define S3P_F  6400     // s3 partials [4 nb][256 m]
#define S4P_F  7424     // s4 partials [4 nb][256 m]
#define G_F    8448     // [256][256]
#define PP_F   73984    // P partials [4 nc][256 m][64 i]

// ---------------------------------------------------------------------------
__global__ __launch_bounds__(256) void k1_kernel(
    const float* __restrict__ x,  const float* __restrict__ W1,
    const float* __restrict__ b1, const float* __restrict__ W2,
    const float* __restrict__ b2, const float* __restrict__ W3,
    float* __restrict__ ws_f, int* __restrict__ cnt) {
    __shared__ __align__(16) float smem[8704];
    int tid = threadIdx.x, b = blockIdx.x;

    if (b < 16) {                     // ---- Gram tile (gr,gc): 1 matmul
        int gr = b >> 2, gc = b & 3;
        float* As = smem;
        float* Bs = smem + 4352;
        for (int idx = tid; idx < 4096; idx += 256) {
            int r = idx >> 6, i = idx & 63;
            As[i * 68 + r] = W1[(gr * 64 + r) * 64 + i];
            Bs[i * 68 + r] = W1[(gc * 64 + r) * 64 + i];
        }
        __syncthreads();
        int r0 = (tid & 15) * 4, c0 = (tid >> 4) * 4;
        float a[4][4] = {};
        for (int i = 0; i < 64; i++) {
            float4 av = *(const float4*)&As[i * 68 + r0];
            float4 bv = *(const float4*)&Bs[i * 68 + c0];
            float ar[4] = {av.x, av.y, av.z, av.w};
            float br[4] = {bv.x, bv.y, bv.z, bv.w};
            #pragma unroll
            for (int rr = 0; rr < 4; rr++)
                #pragma unroll
                for (int cc = 0; cc < 4; cc++)
                    a[rr][cc] = fmaf(ar[rr], br[cc], a[rr][cc]);
        }
        float* G = ws_f + G_F;
        #pragma unroll
        for (int rr = 0; rr < 4; rr++)
            #pragma unroll
            for (int cc = 0; cc < 4; cc++)
                G[(gr * 64 + r0 + rr) * 256 + gc * 64 + c0 + cc] = a[rr][cc];
    } else if (b < 48) {              // ---- P-partial (mbp, nc): 1 matmul
        int pb = b - 16, mbp = pb >> 2, nc = pb & 3, m0 = mbp * 32;
        float* Wc  = smem;            // [64n][34] m-minor
        float* Bc  = smem + 2176;     // [64n][68] i-minor
        float* c1s = smem + 6528;     // 64 (this nc chunk only)
        float* xs  = smem + 6592;     // 64
        if (tid < 64) xs[tid] = x[tid];
        __syncthreads();
        if (tid < 64) {               // local c1 for rows nc*64..nc*64+63
            int n = nc * 64 + tid;
            const float4* row = (const float4*)(W1 + n * 64);
            const float4* xv4 = (const float4*)xs;
            float u0 = b1[n];
            #pragma unroll
            for (int k = 0; k < 16; k++) {
                float4 w = row[k], xv = xv4[k];
                u0 += w.x * xv.x + w.y * xv.y + w.z * xv.z + w.w * xv.w;
            }
            float T = tanhf(u0);
            c1s[tid] = 1.f - T * T;
        }
        for (int idx = tid; idx < 2048; idx += 256) {   // W2 chunk
            int mm = idx >> 6, nn = idx & 63;
            Wc[nn * 34 + mm] = W2[(m0 + mm) * 256 + nc * 64 + nn];
        }
        __syncthreads();
        for (int idx = tid; idx < 4096; idx += 256) {   // c1-scaled W1 chunk
            int nn = idx >> 6, ii = idx & 63;
            Bc[nn * 68 + ii] = c1s[nn] * W1[(nc * 64 + nn) * 64 + ii];
        }
        __syncthreads();
        float acc2[2][4] = {};
        int tm2 = (tid & 15) * 2, ti = (tid >> 4) * 4;
        for (int nn = 0; nn < 64; nn++) {
            float2 a2 = *(const float2*)&Wc[nn * 34 + tm2];
            float4 b4 = *(const float4*)&Bc[nn * 68 + ti];
            float br[4] = {b4.x, b4.y, b4.z, b4.w};
            #pragma unroll
            for (int j = 0; j < 4; j++) {
                acc2[0][j] = fmaf(a2.x, br[j], acc2[0][j]);
                acc2[1][j] = fmaf(a2.y, br[j], acc2[1][j]);
            }
        }
        float* PPc = ws_f + PP_F + nc * 16384;
        #pragma unroll
        for (int j = 0; j < 4; j++) {
            PPc[(m0 + tm2) * 64 + ti + j]     = acc2[0][j];   // write-once
            PPc[(m0 + tm2 + 1) * 64 + ti + j] = acc2[1][j];
        }
    } else if (b < 52) {              // ---- E, q, s5 (local coefs)
        int m0 = (b - 48) * 64;
        float* Ws   = smem;           // [64n][65]
        float* h0s  = smem + 4160;
        float* aqs  = smem + 4416;
        float* a5s  = smem + 4672;
        float* part = smem + 4928;    // [3][256]
        float* xs   = smem + 5696;    // 64
        if (tid < 64) xs[tid] = x[tid];
        __syncthreads();
        {
            const float4* row = (const float4*)(W1 + tid * 64);
            const float4* xv4 = (const float4*)xs;
            float u0 = b1[tid], r2v = 0.f;
            #pragma unroll
            for (int k = 0; k < 16; k++) {
                float4 w = row[k], xv = xv4[k];
                u0  += w.x * xv.x + w.y * xv.y + w.z * xv.z + w.w * xv.w;
                r2v += w.x * w.x + w.y * w.y + w.z * w.z + w.w * w.w;
            }
            float T = tanhf(u0), s = 1.f - T * T;
            float c2 = -2.f * T * s;
            float c4 = s * T * (16.f - 24.f * T * T);
            h0s[tid] = T;
            aqs[tid] = c2 * r2v;
            a5s[tid] = c4 * r2v * r2v;
        }
        int mm = tid & 63, nq = tid >> 6;
        float pv = 0.f, pq = 0.f, p5 = 0.f;
        for (int nc = 0; nc < 4; nc++) {
            __syncthreads();
            for (int idx = tid; idx < 4096; idx += 256) {
                int m2 = idx >> 6, nn = idx & 63;
                Ws[nn * 65 + m2] = W2[(m0 + m2) * 256 + nc * 64 + nn];
            }
            __syncthreads();
            #pragma unroll
            for (int k = 0; k < 16; k++) {
                int nn = nq * 16 + k, n = nc * 64 + nn;
                float wv = Ws[nn * 65 + mm];
                pv = fmaf(wv, h0s[n], pv);
                pq = fmaf(wv, aqs[n], pq);
                p5 = fmaf(wv, a5s[n], p5);
            }
        }
        part[nq * 64 + mm]       = pv;
        part[256 + nq * 64 + mm] = pq;
        part[512 + nq * 64 + mm] = p5;
        __syncthreads();
        if (tid < 64) {
            int m = m0 + tid;
            float v  = b2[m] + part[tid] + part[64 + tid] + part[128 + tid] + part[192 + tid];
            float q  = part[256 + tid] + part[320 + tid] + part[384 + tid] + part[448 + tid];
            float s5 = part[512 + tid] + part[576 + tid] + part[640 + tid] + part[704 + tid];
            float T2 = tanhf(v), s2 = 1.f - T2 * T2, w3 = W3[m];
            ws_f[E_F + m]       = w3 * s2;
            ws_f[E_F + 256 + m] = -2.f * w3 * T2 * s2;
            ws_f[E_F + 512 + m] = w3 * s2 * (6.f * T2 * T2 - 2.f);
            ws_f[E_F + 768 + m] = w3 * s2 * T2 * (16.f - 24.f * T2 * T2);
            ws_f[Q_F + m]  = q;
            ws_f[S5_F + m] = s5;
        }
    } else {                          // ---- coef: c2, c3*r2 -> ws; cnt = 0
        float* xs = smem;
        if (tid < 64) xs[tid] = x[tid];
        __syncthreads();
        const float4* row = (const float4*)(W1 + tid * 64);
        const float4* xv4 = (const float4*)xs;
        float u0 = b1[tid], r2v = 0.f;
        #pragma unroll
        for (int k = 0; k < 16; k++) {
            float4 w = row[k], xv = xv4[k];
            u0  += w.x * xv.x + w.y * xv.y + w.z * xv.z + w.w * xv.w;
            r2v += w.x * w.x + w.y * w.y + w.z * w.z + w.w * w.w;
        }
        float T = tanhf(u0), s = 1.f - T * T;
        ws_f[CV_F + tid]       = -2.f * T * s;              // c2
        ws_f[CV_F + 256 + tid] = s * (6.f * T * T - 2.f) * r2v;  // c3*r2
        if (tid == 0) *cnt = 0;
    }
}

// ---------------------------------------------------------------------------
// k2: 64 u-tiles + 16 T-tiles, each exactly ONE 64^3 matmul; ticket combine.
// ---------------------------------------------------------------------------
__global__ __launch_bounds__(256) void k2_kernel(
    const float* __restrict__ W1, const float* __restrict__ W2,
    float* __restrict__ ws_f, int* __restrict__ cnt, float* __restrict__ out) {
    __shared__ __align__(16) float smem[13248];
    __shared__ int lastFlag;
    __shared__ double dsum[4];
    int tid = threadIdx.x, b = blockIdx.x;
    const float* c2g  = ws_f + CV_F;
    const float* c34g = ws_f + CV_F + 256;

    if (b < 64) {              // ---- u-tile (kb, mb, nc): 1 matmul
        int kb = b >> 4, mb = (b >> 2) & 3, nc = b & 3;
        float* Cs  = smem;            // [n][68] k-minor: c2[n]*G[k][n]^2
        float* Bs  = smem + 4352;     // [n][68] m-minor: W2 chunk
        float* W2k = smem + 8704;     // [m][68] k: W2 epilogue chunk
        const float* G = ws_f + G_F;
        for (int idx = tid; idx < 4096; idx += 256) {
            int r = idx >> 6, c = idx & 63;               // r=k-local, c=n-local
            float gv = G[(kb * 64 + r) * 256 + nc * 64 + c];
            Cs[c * 68 + r] = c2g[nc * 64 + c] * gv * gv;
        }
        for (int idx = tid; idx < 4096; idx += 256) {
            int m_ = idx >> 6, n_ = idx & 63;
            Bs[n_ * 68 + m_] = W2[(mb * 64 + m_) * 256 + nc * 64 + n_];
        }
        for (int idx = tid; idx < 4096; idx += 256) {
            int m_ = idx >> 6, k_ = idx & 63;
            W2k[m_ * 68 + k_] = W2[(mb * 64 + m_) * 256 + kb * 64 + k_];
        }
        __syncthreads();
        int r0 = (tid & 15) * 4, c0 = (tid >> 4) * 4;     // r0: k, c0: m
        float a[4][4] = {};
        for (int nn = 0; nn < 64; nn++) {
            float4 av = *(const float4*)&Cs[nn * 68 + r0];
            float4 bv = *(const float4*)&Bs[nn * 68 + c0];
            float ar[4] = {av.x, av.y, av.z, av.w};
            float br[4] = {bv.x, bv.y, bv.z, bv.w};
            #pragma unroll
            for (int rr = 0; rr < 4; rr++)
                #pragma unroll
                for (int cc = 0; cc < 4; cc++)
                    a[rr][cc] = fmaf(ar[rr], br[cc], a[rr][cc]);
        }
        #pragma unroll
        for (int cc = 0; cc < 4; cc++) {                  // u partial per m
            float up = 0.f;
            #pragma unroll
            for (int rr = 0; rr < 4; rr++)
                up += a[rr][cc] * c2g[kb * 64 + r0 + rr] * W2k[(c0 + cc) * 68 + r0 + rr];
            up += __shfl_xor(up, 8, 16);
            up += __shfl_xor(up, 4, 16);
            up += __shfl_xor(up, 2, 16);
            up += __shfl_xor(up, 1, 16);
            if ((tid & 15) == 0)
                ws_f[UP_F + (kb * 4 + nc) * 256 + mb * 64 + c0 + cc] = up;  // write-once
        }
    } else {                   // ---- T-tile (mb, nb): 1 matmul
        int tb = b - 64, mb = tb >> 2, nb = tb & 3;
        float* Pt   = smem;           // [i][68] m-minor: full P tile
        float* As   = smem + 4352;    // [ii][68] n-minor: W1 tile
        float* W2s  = smem + 8704;    // [m][68] n
        float* c2s  = smem + 13056;   // 64
        float* c34s = smem + 13120;   // 64
        const float* PP = ws_f + PP_F;
        for (int idx = tid; idx < 4096; idx += 256) {     // sum 4 P partials
            int ml = idx >> 6, i = idx & 63;
            int mg = (mb * 64 + ml) * 64 + i;
            Pt[i * 68 + ml] = PP[mg] + PP[16384 + mg] + PP[32768 + mg] + PP[49152 + mg];
        }
        for (int idx = tid; idx < 4096; idx += 256) {
            int nl = idx >> 6, ii = idx & 63;
            As[ii * 68 + nl] = W1[(nb * 64 + nl) * 64 + ii];
        }
        for (int idx = tid; idx < 4096; idx += 256) {
            int m_ = idx >> 6, n_ = idx & 63;
            W2s[m_ * 68 + n_] = W2[(mb * 64 + m_) * 256 + nb * 64 + n_];
        }
        if (tid < 64) {
            c2s[tid]  = c2g[nb * 64 + tid];
            c34s[tid] = c34g[nb * 64 + tid];
        }
        __syncthreads();
        int m0t = (tid >> 4) * 4, n0t = (tid & 15) * 4;
        float t4[4][4] = {};
        for (int ii = 0; ii < 64; ii++) {
            float4 av = *(const float4*)&Pt[ii * 68 + m0t];
            float4 bv = *(const float4*)&As[ii * 68 + n0t];
            float ar[4] = {av.x, av.y, av.z, av.w};
            float br[4] = {bv.x, bv.y, bv.z, bv.w};
            #pragma unroll
            for (int rr = 0; rr < 4; rr++)
                #pragma unroll
                for (int cc = 0; cc < 4; cc++)
                    t4[rr][cc] = fmaf(ar[rr], br[cc], t4[rr][cc]);
        }
        #pragma unroll
        for (int rr = 0; rr < 4; rr++) {                  // s3/s4 partials
            float s3p = 0.f, s4p = 0.f;
            #pragma unroll
            for (int cc = 0; cc < 4; cc++) {
                float wv = W2s[(m0t + rr) * 68 + n0t + cc];
                float t  = t4[rr][cc];
                s3p = fmaf(c2s[n0t + cc] * wv, t * t, s3p);
                s4p = fmaf(c34s[n0t + cc] * wv, t, s4p);
            }
            s3p += __shfl_xor(s3p, 8, 16); s4p += __shfl_xor(s4p, 8, 16);
            s3p += __shfl_xor(s3p, 4, 16); s4p += __shfl_xor(s4p, 4, 16);
            s3p += __shfl_xor(s3p, 2, 16); s4p += __shfl_xor(s4p, 2, 16);
            s3p += __shfl_xor(s3p, 1, 16); s4p += __shfl_xor(s4p, 1, 16);
            if ((tid & 15) == 0) {
                ws_f[S3P_F + nb * 256 + mb * 64 + m0t + rr] = s3p;  // write-once
                ws_f[S4P_F + nb * 256 + mb * 64 + m0t + rr] = s4p;  // write-once
            }
        }
        if (nb == 0 && tid < 64) {                        // p2 from full P
            float p = 0.f;
            for (int i = 0; i < 64; i++) {
                float v = Pt[i * 68 + tid];
                p = fmaf(v, v, p);
            }
            ws_f[P2_F + mb * 64 + tid] = p;               // write-once
        }
    }

    // ---- ticket: last-arriving block combines (no waiting, no co-residency)
    __threadfence();
    if (tid == 0) lastFlag = (atomicAdd(cnt, 1) == 79) ? 1 : 0;
    __syncthreads();
    if (lastFlag) {
        __threadfence();
        volatile float* wsv = ws_f;
        int m = tid;
        float um = 0.f;
        #pragma unroll
        for (int s = 0; s < 16; s++) um += wsv[UP_F + s * 256 + m];
        float s3m = wsv[S3P_F + m] + wsv[S3P_F + 256 + m] + wsv[S3P_F + 512 + m] + wsv[S3P_F + 768 + m];
        float s4m = wsv[S4P_F + m] + wsv[S4P_F + 256 + m] + wsv[S4P_F + 512 + m] + wsv[S4P_F + 768 + m];
        float p2 = wsv[P2_F + m], q = wsv[Q_F + m], s5 = wsv[S5_F + m];
        float E1 = wsv[E_F + m], E2 = wsv[E_F + 256 + m];
        float E3 = wsv[E_F + 512 + m], E4 = wsv[E_F + 768 + m];
        float y = E4 * p2 * p2
                + E3 * (2.f * q * p2 + 4.f * s3m)
                + E2 * (q * q + 2.f * um + 4.f * s4m)
                + E1 * s5;
        double part = (double)y;
        for (int off = 32; off > 0; off >>= 1) part += __shfl_down(part, off, 64);
        if ((tid & 63) == 0) dsum[tid >> 6] = part;
        __syncthreads();
        if (tid == 0) out[0] = (float)(dsum[0] + dsum[1] + dsum[2] + dsum[3]);
    }
}

// ---------------------------------------------------------------------------
extern "C" void kernel_launch(void* const* d_in, const int* in_sizes, int n_in,
                              void* d_out, int out_size, void* d_ws, size_t ws_size,
                              hipStream_t stream) {
    const float* x  = (const float*)d_in[0];
    const float* W1 = (const float*)d_in[1];
    const float* b1 = (const float*)d_in[2];
    const float* W2 = (const float*)d_in[3];
    const float* b2 = (const float*)d_in[4];
    const float* W3 = (const float*)d_in[5];
    // b3 does not affect the 4th derivative

    char*  ws   = (char*)d_ws;
    int*   cnt  = (int*)ws;
    float* ws_f = (float*)(ws + 16);
    float* out  = (float*)d_out;

    k1_kernel<<<53, 256, 0, stream>>>(x, W1, b1, W2, b2, W3, ws_f, cnt);
    k2_kernel<<<80, 256, 0, stream>>>(W1, W2, ws_f, cnt, out);
}